// Round 5
// baseline (2600.067 us; speedup 1.0000x reference)
//
#include <hip/hip_runtime.h>

// WRGCN: out[t] = sum_r (sum_{e:tgt=t,rel=r} ew_e * X[src_e]) @ W_r + X[t] @ W_self + P @ bias
// Counting-sort edges by key = r*N + tgt (relation-major). k_main: 512 threads / 64 targets,
// per relation: batch-4 independent strided gathers -> f32 LDS tile (ds_add, conflict-free
// lane*4 addresses) -> MFMA with f32->bf16 pack-in-fragment. Self term streams from global X.

#define N_ENT 200000
#define D 256
#define R_REL 8
#define E_EDGE 150000
#define TOT_E (R_REL * E_EDGE)        // 1,200,000
#define MKEY (N_ENT * R_REL)          // 1,600,000
#define SCAN_B 1024
#define NBLK_SCAN ((MKEY + SCAN_B - 1) / SCAN_B)   // 1563

typedef __bf16 bf16x8 __attribute__((ext_vector_type(8)));
typedef unsigned short u16x8 __attribute__((ext_vector_type(8)));
typedef float f32x4 __attribute__((ext_vector_type(4)));

__device__ __forceinline__ unsigned short f2bf(float f) {
  unsigned int u = __builtin_bit_cast(unsigned int, f);
  u += 0x7FFFu + ((u >> 16) & 1u);   // RNE (inputs finite)
  return (unsigned short)(u >> 16);
}
__device__ __forceinline__ float bf2f(unsigned short u) {
  return __builtin_bit_cast(float, ((unsigned)u) << 16);
}
__device__ __forceinline__ f32x4 mfma16(u16x8 a, u16x8 b, f32x4 c) {
  return __builtin_amdgcn_mfma_f32_16x16x32_bf16(
      __builtin_bit_cast(bf16x8, a), __builtin_bit_cast(bf16x8, b), c, 0, 0, 0);
}
__device__ __forceinline__ u16x8 pack8(f32x4 lo, f32x4 hi) {
  bf16x8 h;
  h[0] = (__bf16)lo[0]; h[1] = (__bf16)lo[1]; h[2] = (__bf16)lo[2]; h[3] = (__bf16)lo[3];
  h[4] = (__bf16)hi[0]; h[5] = (__bf16)hi[1]; h[6] = (__bf16)hi[2]; h[7] = (__bf16)hi[3];
  return __builtin_bit_cast(u16x8, h);
}

// ---- X (f32) -> Xh (bf16) ----
__global__ __launch_bounds__(256) void k_cvt_x(const float* __restrict__ x,
                                               unsigned short* __restrict__ xh) {
  int i = blockIdx.x * 256 + threadIdx.x;
  const float4* xv = (const float4*)x;
  float4 a = xv[2 * i], b = xv[2 * i + 1];
  uint4 o;
  o.x = (unsigned)f2bf(a.x) | ((unsigned)f2bf(a.y) << 16);
  o.y = (unsigned)f2bf(a.z) | ((unsigned)f2bf(a.w) << 16);
  o.z = (unsigned)f2bf(b.x) | ((unsigned)f2bf(b.y) << 16);
  o.w = (unsigned)f2bf(b.z) | ((unsigned)f2bf(b.w) << 16);
  ((uint4*)xh)[i] = o;
}

// ---- Weights -> bf16 MFMA B-fragment order. tile 0..7 = W_r, 8 = self ----
__global__ __launch_bounds__(256) void k_cvt_w(const float* __restrict__ relw,
                                               const float* __restrict__ selfw,
                                               unsigned short* __restrict__ wf) {
  int t = blockIdx.x * 256 + threadIdx.x;   // 9*8*16*64 = 73728
  int rel = t >> 13;
  int rem = t & 8191;
  int kb = rem >> 10;
  int nb = (rem >> 6) & 15;
  int lane = rem & 63;
  const float* W = (rel < R_REL) ? (relw + rel * D * D) : selfw;
  int k0 = kb * 32 + (lane >> 4) * 8;
  int n = nb * 16 + (lane & 15);
  unsigned int o[4];
#pragma unroll
  for (int jj = 0; jj < 4; ++jj) {
    unsigned lo = f2bf(W[(k0 + 2 * jj) * D + n]);
    unsigned hi = f2bf(W[(k0 + 2 * jj + 1) * D + n]);
    o[jj] = lo | (hi << 16);
  }
  ((uint4*)wf)[t] = make_uint4(o[0], o[1], o[2], o[3]);
}

// ---- bias -> B-fragment tile for K=8 presence MFMA ----
__global__ __launch_bounds__(256) void k_cvt_bias(const float* __restrict__ bias,
                                                  unsigned short* __restrict__ bb) {
  int t = blockIdx.x * 256 + threadIdx.x;   // 1024
  int nb = t >> 6, lane = t & 63;
  int lk = lane >> 4, n = nb * 16 + (lane & 15);
  unsigned int o[4];
#pragma unroll
  for (int jj = 0; jj < 4; ++jj) {
    unsigned lo = 0, hi = 0;
    if (lk == 0) {
      lo = f2bf(bias[(2 * jj) * D + n]);
      hi = f2bf(bias[(2 * jj + 1) * D + n]);
    }
    o[jj] = lo | (hi << 16);
  }
  ((uint4*)bb)[t] = make_uint4(o[0], o[1], o[2], o[3]);
}

// ---- histogram over key = r*N + tgt ----
__global__ __launch_bounds__(256) void k_hist(const int* __restrict__ ei,
                                              unsigned* __restrict__ counts) {
  int t = blockIdx.x * 256 + threadIdx.x;
  if (t >= TOT_E) return;
  int r = t / E_EDGE, e = t - r * E_EDGE;
  int tgt = ei[(r * 2 + 1) * E_EDGE + e];
  atomicAdd(&counts[r * N_ENT + tgt], 1u);
}

// ---- exclusive scan (3 kernels) ----
__global__ __launch_bounds__(256) void k_scan1(const unsigned* __restrict__ cnt,
                                               unsigned* __restrict__ off,
                                               unsigned* __restrict__ aux) {
  __shared__ unsigned sc[256];
  int tid = threadIdx.x;
  int base = blockIdx.x * SCAN_B + tid * 4;
  unsigned v[4];
#pragma unroll
  for (int j = 0; j < 4; ++j) v[j] = (base + j < MKEY) ? cnt[base + j] : 0u;
  unsigned s = v[0] + v[1] + v[2] + v[3];
  sc[tid] = s;
  __syncthreads();
  for (int o = 1; o < 256; o <<= 1) {
    unsigned t = (tid >= o) ? sc[tid - o] : 0u;
    __syncthreads();
    sc[tid] += t;
    __syncthreads();
  }
  unsigned excl = sc[tid] - s;
  if (tid == 255) aux[blockIdx.x] = sc[255];
#pragma unroll
  for (int j = 0; j < 4; ++j) {
    if (base + j < MKEY) off[base + j] = excl;
    excl += v[j];
  }
}

__global__ __launch_bounds__(256) void k_scan2(unsigned* __restrict__ aux) {
  __shared__ unsigned sc[256];
  int tid = threadIdx.x;
  int base = tid * 7;
  unsigned v[7];
#pragma unroll
  for (int j = 0; j < 7; ++j) v[j] = (base + j < NBLK_SCAN) ? aux[base + j] : 0u;
  unsigned s = 0;
#pragma unroll
  for (int j = 0; j < 7; ++j) s += v[j];
  sc[tid] = s;
  __syncthreads();
  for (int o = 1; o < 256; o <<= 1) {
    unsigned t = (tid >= o) ? sc[tid - o] : 0u;
    __syncthreads();
    sc[tid] += t;
    __syncthreads();
  }
  unsigned excl = sc[tid] - s;
#pragma unroll
  for (int j = 0; j < 7; ++j) {
    if (base + j < NBLK_SCAN) aux[base + j] = excl;
    excl += v[j];
  }
}

__global__ __launch_bounds__(256) void k_scan3(unsigned* __restrict__ off,
                                               const unsigned* __restrict__ aux) {
  unsigned add = aux[blockIdx.x];
  int base = blockIdx.x * SCAN_B + threadIdx.x * 4;
  if (base + 3 < MKEY) {
    uint4* p = (uint4*)(off + base);
    uint4 x = *p;
    x.x += add; x.y += add; x.z += add; x.w += add;
    *p = x;
  } else {
    for (int j = 0; j < 4; ++j)
      if (base + j < MKEY) off[base + j] += add;
  }
}

// ---- scatter packed (src | (tgt&63)<<18, ew); off becomes segment ENDs ----
__global__ __launch_bounds__(256) void k_scatter(const int* __restrict__ ei,
                                                 const float* __restrict__ ew,
                                                 unsigned* __restrict__ off,
                                                 unsigned* __restrict__ spack,
                                                 float* __restrict__ sewt) {
  int t = blockIdx.x * 256 + threadIdx.x;
  if (t >= TOT_E) return;
  int r = t / E_EDGE, e = t - r * E_EDGE;
  int tgt = ei[(r * 2 + 1) * E_EDGE + e];
  int src = ei[(r * 2) * E_EDGE + e];
  float w = ew[t];
  unsigned pos = atomicAdd(&off[r * N_ENT + tgt], 1u);
  spack[pos] = (unsigned)src | ((unsigned)(tgt & 63) << 18);
  sewt[pos] = w;
}

// ---- fused main: 512 threads, 64 targets/block ----
__global__ __launch_bounds__(512, 4) void k_main(const unsigned short* __restrict__ xh,
                                                 const unsigned short* __restrict__ wf,
                                                 const unsigned short* __restrict__ bbf,
                                                 const unsigned* __restrict__ counts,
                                                 const unsigned* __restrict__ off_end,
                                                 const unsigned* __restrict__ spack,
                                                 const float* __restrict__ sewt,
                                                 float* __restrict__ out) {
  __shared__ __align__(16) unsigned char Ls[65536];   // 64x256 f32 tile, XOR-swizzled
  __shared__ unsigned rng[8][2];
  int n0 = blockIdx.x * 64;
  int tid = threadIdx.x;
  int w = tid >> 6, lane = tid & 63;
  int lm = lane & 15, lk = lane >> 4;
  int rbase = (w >> 2) * 32;          // wave's 32-row half
  int cbase = (w & 3) * 4;            // wave's 4 nb columns (64 cols)

  if (tid < 8) {
    int k0 = tid * N_ENT + n0;
    rng[tid][0] = off_end[k0] - counts[k0];   // range start
    rng[tid][1] = off_end[k0 + 63];           // range end
  }

  f32x4 acc[2][4] = {};

  // ---- self phase: A-frags direct from global bf16 X ----
  {
    const unsigned short* wfb = wf + 8 * 65536;
#pragma unroll
    for (int kb = 0; kb < 8; ++kb) {
      u16x8 a[2], b[4];
#pragma unroll
      for (int mi = 0; mi < 2; ++mi)
        a[mi] = *(const u16x8*)(xh + (size_t)(n0 + rbase + mi * 16 + lm) * 256 + kb * 32 + lk * 8);
#pragma unroll
      for (int ni = 0; ni < 4; ++ni)
        b[ni] = *(const u16x8*)(wfb + ((kb * 16 + cbase + ni) * 64 + lane) * 8);
#pragma unroll
      for (int mi = 0; mi < 2; ++mi)
#pragma unroll
        for (int ni = 0; ni < 4; ++ni)
          acc[mi][ni] = mfma16(a[mi], b[ni], acc[mi][ni]);
    }
  }
  __syncthreads();   // rng ready

  for (int r = 0; r < 8; ++r) {
    // zero f32 tile (conflict-free 16B stores)
    f32x4 z4 = {0.f, 0.f, 0.f, 0.f};
#pragma unroll
    for (int z = 0; z < 8; ++z)
      *(f32x4*)(Ls + z * 8192 + tid * 16) = z4;
    __syncthreads();

    // batch-4 edge gather-accumulate: wave w covers offsets w + 8u + 32k
    unsigned s0 = rng[r][0], e0 = rng[r][1];
    for (unsigned base = s0 + (unsigned)w; base < e0; base += 32) {
      unsigned pkv[4];
      float wtv[4];
#pragma unroll
      for (int u = 0; u < 4; ++u) {
        unsigned ii = base + (unsigned)u * 8u;
        bool v = ii < e0;
        pkv[u] = v ? spack[ii] : 0u;
        wtv[u] = v ? sewt[ii] : 0.0f;
      }
      unsigned short xs[4][4];
#pragma unroll
      for (int u = 0; u < 4; ++u) {
        const unsigned short* xr = xh + (size_t)(pkv[u] & 0x3FFFFu) * 256 + lane;
        xs[u][0] = xr[0];
        xs[u][1] = xr[64];
        xs[u][2] = xr[128];
        xs[u][3] = xr[192];
      }
#pragma unroll
      for (int u = 0; u < 4; ++u) {
        unsigned g = pkv[u] >> 18;
        unsigned bb = g * 1024u, sw = (g & 7u) << 4;
        float wt = wtv[u];
        atomicAdd((float*)(Ls + ((bb + lane * 4) ^ sw)), wt * bf2f(xs[u][0]));
        atomicAdd((float*)(Ls + ((bb + 256 + lane * 4) ^ sw)), wt * bf2f(xs[u][1]));
        atomicAdd((float*)(Ls + ((bb + 512 + lane * 4) ^ sw)), wt * bf2f(xs[u][2]));
        atomicAdd((float*)(Ls + ((bb + 768 + lane * 4) ^ sw)), wt * bf2f(xs[u][3]));
      }
    }
    __syncthreads();

    // MFMA: A-frags = 2 x b128 f32 reads + pack to bf16
    const unsigned short* wfb = wf + r * 65536;
#pragma unroll
    for (int kb = 0; kb < 8; ++kb) {
      u16x8 a[2], b[4];
#pragma unroll
      for (int mi = 0; mi < 2; ++mi) {
        int row = rbase + mi * 16 + lm;
        unsigned c4 = (unsigned)(kb * 128 + lk * 32);
        unsigned sw = (unsigned)((row & 7) << 4);
        f32x4 lo = *(const f32x4*)(Ls + ((row * 1024 + c4) ^ sw));
        f32x4 hi = *(const f32x4*)(Ls + ((row * 1024 + c4 + 16) ^ sw));
        a[mi] = pack8(lo, hi);
      }
#pragma unroll
      for (int ni = 0; ni < 4; ++ni)
        b[ni] = *(const u16x8*)(wfb + ((kb * 16 + cbase + ni) * 64 + lane) * 8);
#pragma unroll
      for (int mi = 0; mi < 2; ++mi)
#pragma unroll
        for (int ni = 0; ni < 4; ++ni)
          acc[mi][ni] = mfma16(a[mi], b[ni], acc[mi][ni]);
    }
    __syncthreads();
  }

  // ---- bias via presence MFMA: P[64x8] @ bias[8x256] ----
  {
    u16x8 bb[4];
#pragma unroll
    for (int ni = 0; ni < 4; ++ni)
      bb[ni] = *(const u16x8*)(bbf + ((cbase + ni) * 64 + lane) * 8);
#pragma unroll
    for (int mi = 0; mi < 2; ++mi) {
      u16x8 pa = {};
      if (lk == 0) {
        int n = n0 + rbase + mi * 16 + lm;
#pragma unroll
        for (int r = 0; r < 8; ++r)
          pa[r] = counts[r * N_ENT + n] ? 0x3F80 : 0;
      }
#pragma unroll
      for (int ni = 0; ni < 4; ++ni)
        acc[mi][ni] = mfma16(pa, bb[ni], acc[mi][ni]);
    }
  }

  // ---- epilogue ----
#pragma unroll
  for (int mi = 0; mi < 2; ++mi)
#pragma unroll
    for (int ni = 0; ni < 4; ++ni) {
      int col = cbase * 16 + ni * 16 + lm;
#pragma unroll
      for (int j = 0; j < 4; ++j) {
        int row = n0 + rbase + mi * 16 + lk * 4 + j;
        out[row * 256 + col] = acc[mi][ni][j];
      }
    }
}

extern "C" void kernel_launch(void* const* d_in, const int* in_sizes, int n_in,
                              void* d_out, int out_size, void* d_ws, size_t ws_size,
                              hipStream_t stream) {
  const float* x = (const float*)d_in[0];
  const float* relw = (const float*)d_in[1];
  const float* selfw = (const float*)d_in[2];
  const float* bias = (const float*)d_in[3];
  const int* ei = (const int*)d_in[4];
  const float* ew = (const float*)d_in[5];
  float* out = (float*)d_out;

  char* ws = (char*)d_ws;
  unsigned short* xh = (unsigned short*)ws;                          // 102,400,000
  unsigned short* wf = (unsigned short*)(ws + 102400000);            //   1,179,648
  unsigned short* bbf = (unsigned short*)(ws + 103579648);           //      16,384
  unsigned* counts = (unsigned*)(ws + 103596032);                    //   6,400,000
  unsigned* offs = (unsigned*)(ws + 109996032);                      //   6,400,000
  unsigned* aux = (unsigned*)(ws + 116396032);                       //       8,192
  unsigned* spack = (unsigned*)(ws + 116404224);                     //   4,800,000
  float* sewt = (float*)(ws + 121204224);                            //   4,800,000

  hipMemsetAsync(counts, 0, (size_t)MKEY * 4, stream);
  k_cvt_x<<<(N_ENT * D) / 2048, 256, 0, stream>>>(x, xh);
  k_cvt_w<<<288, 256, 0, stream>>>(relw, selfw, wf);
  k_cvt_bias<<<4, 256, 0, stream>>>(bias, bbf);
  k_hist<<<(TOT_E + 255) / 256, 256, 0, stream>>>(ei, counts);
  k_scan1<<<NBLK_SCAN, 256, 0, stream>>>(counts, offs, aux);
  k_scan2<<<1, 256, 0, stream>>>(aux);
  k_scan3<<<NBLK_SCAN, 256, 0, stream>>>(offs, aux);
  k_scatter<<<(TOT_E + 255) / 256, 256, 0, stream>>>(ei, ew, offs, spack, sewt);
  k_main<<<N_ENT / 64, 512, 0, stream>>>(xh, wf, bbf, counts, offs, spack, sewt, out);
}

// Round 6
// 942.084 us; speedup vs baseline: 2.7599x; 2.7599x over previous
//
#include <hip/hip_runtime.h>

// WRGCN: out[t] = sum_r (sum_{e:tgt=t,rel=r} ew_e * X[src_e]) @ W_r + X[t] @ W_self + P @ bias
// Counting-sort edges by key = r*N + tgt. k_main: 512 thr / 64 targets; each wave owns 8
// target rows; per relation: 8-key register-interleaved gather-accumulate (8 independent
// gathers in flight, no LDS atomics), one bf16 write/key into swizzled As, then MFMA.

#define N_ENT 200000
#define D 256
#define R_REL 8
#define E_EDGE 150000
#define TOT_E (R_REL * E_EDGE)        // 1,200,000
#define MKEY (N_ENT * R_REL)          // 1,600,000
#define SCAN_B 1024
#define NBLK_SCAN ((MKEY + SCAN_B - 1) / SCAN_B)   // 1563

typedef __bf16 bf16x8 __attribute__((ext_vector_type(8)));
typedef unsigned short u16x8 __attribute__((ext_vector_type(8)));
typedef float f32x4 __attribute__((ext_vector_type(4)));

__device__ __forceinline__ unsigned short f2bf(float f) {
  unsigned int u = __builtin_bit_cast(unsigned int, f);
  u += 0x7FFFu + ((u >> 16) & 1u);   // RNE (inputs finite)
  return (unsigned short)(u >> 16);
}
__device__ __forceinline__ float bf2f(unsigned short u) {
  return __builtin_bit_cast(float, ((unsigned)u) << 16);
}
__device__ __forceinline__ f32x4 mfma16(u16x8 a, u16x8 b, f32x4 c) {
  return __builtin_amdgcn_mfma_f32_16x16x32_bf16(
      __builtin_bit_cast(bf16x8, a), __builtin_bit_cast(bf16x8, b), c, 0, 0, 0);
}

// ---- X (f32) -> Xh (bf16) ----
__global__ __launch_bounds__(256) void k_cvt_x(const float* __restrict__ x,
                                               unsigned short* __restrict__ xh) {
  int i = blockIdx.x * 256 + threadIdx.x;
  const float4* xv = (const float4*)x;
  float4 a = xv[2 * i], b = xv[2 * i + 1];
  uint4 o;
  o.x = (unsigned)f2bf(a.x) | ((unsigned)f2bf(a.y) << 16);
  o.y = (unsigned)f2bf(a.z) | ((unsigned)f2bf(a.w) << 16);
  o.z = (unsigned)f2bf(b.x) | ((unsigned)f2bf(b.y) << 16);
  o.w = (unsigned)f2bf(b.z) | ((unsigned)f2bf(b.w) << 16);
  ((uint4*)xh)[i] = o;
}

// ---- Weights -> bf16 MFMA B-fragment order. tile 0..7 = W_r, 8 = self ----
__global__ __launch_bounds__(256) void k_cvt_w(const float* __restrict__ relw,
                                               const float* __restrict__ selfw,
                                               unsigned short* __restrict__ wf) {
  int t = blockIdx.x * 256 + threadIdx.x;   // 9*8*16*64 = 73728
  int rel = t >> 13;
  int rem = t & 8191;
  int kb = rem >> 10;
  int nb = (rem >> 6) & 15;
  int lane = rem & 63;
  const float* W = (rel < R_REL) ? (relw + rel * D * D) : selfw;
  int k0 = kb * 32 + (lane >> 4) * 8;
  int n = nb * 16 + (lane & 15);
  unsigned int o[4];
#pragma unroll
  for (int jj = 0; jj < 4; ++jj) {
    unsigned lo = f2bf(W[(k0 + 2 * jj) * D + n]);
    unsigned hi = f2bf(W[(k0 + 2 * jj + 1) * D + n]);
    o[jj] = lo | (hi << 16);
  }
  ((uint4*)wf)[t] = make_uint4(o[0], o[1], o[2], o[3]);
}

// ---- bias -> B-fragment tile for K=8 presence MFMA ----
__global__ __launch_bounds__(256) void k_cvt_bias(const float* __restrict__ bias,
                                                  unsigned short* __restrict__ bb) {
  int t = blockIdx.x * 256 + threadIdx.x;   // 1024
  int nb = t >> 6, lane = t & 63;
  int lk = lane >> 4, n = nb * 16 + (lane & 15);
  unsigned int o[4];
#pragma unroll
  for (int jj = 0; jj < 4; ++jj) {
    unsigned lo = 0, hi = 0;
    if (lk == 0) {
      lo = f2bf(bias[(2 * jj) * D + n]);
      hi = f2bf(bias[(2 * jj + 1) * D + n]);
    }
    o[jj] = lo | (hi << 16);
  }
  ((uint4*)bb)[t] = make_uint4(o[0], o[1], o[2], o[3]);
}

// ---- histogram over key = r*N + tgt ----
__global__ __launch_bounds__(256) void k_hist(const int* __restrict__ ei,
                                              unsigned* __restrict__ counts) {
  int t = blockIdx.x * 256 + threadIdx.x;
  if (t >= TOT_E) return;
  int r = t / E_EDGE, e = t - r * E_EDGE;
  int tgt = ei[(r * 2 + 1) * E_EDGE + e];
  atomicAdd(&counts[r * N_ENT + tgt], 1u);
}

// ---- exclusive scan (3 kernels) ----
__global__ __launch_bounds__(256) void k_scan1(const unsigned* __restrict__ cnt,
                                               unsigned* __restrict__ off,
                                               unsigned* __restrict__ aux) {
  __shared__ unsigned sc[256];
  int tid = threadIdx.x;
  int base = blockIdx.x * SCAN_B + tid * 4;
  unsigned v[4];
#pragma unroll
  for (int j = 0; j < 4; ++j) v[j] = (base + j < MKEY) ? cnt[base + j] : 0u;
  unsigned s = v[0] + v[1] + v[2] + v[3];
  sc[tid] = s;
  __syncthreads();
  for (int o = 1; o < 256; o <<= 1) {
    unsigned t = (tid >= o) ? sc[tid - o] : 0u;
    __syncthreads();
    sc[tid] += t;
    __syncthreads();
  }
  unsigned excl = sc[tid] - s;
  if (tid == 255) aux[blockIdx.x] = sc[255];
#pragma unroll
  for (int j = 0; j < 4; ++j) {
    if (base + j < MKEY) off[base + j] = excl;
    excl += v[j];
  }
}

__global__ __launch_bounds__(256) void k_scan2(unsigned* __restrict__ aux) {
  __shared__ unsigned sc[256];
  int tid = threadIdx.x;
  int base = tid * 7;
  unsigned v[7];
#pragma unroll
  for (int j = 0; j < 7; ++j) v[j] = (base + j < NBLK_SCAN) ? aux[base + j] : 0u;
  unsigned s = 0;
#pragma unroll
  for (int j = 0; j < 7; ++j) s += v[j];
  sc[tid] = s;
  __syncthreads();
  for (int o = 1; o < 256; o <<= 1) {
    unsigned t = (tid >= o) ? sc[tid - o] : 0u;
    __syncthreads();
    sc[tid] += t;
    __syncthreads();
  }
  unsigned excl = sc[tid] - s;
#pragma unroll
  for (int j = 0; j < 7; ++j) {
    if (base + j < NBLK_SCAN) aux[base + j] = excl;
    excl += v[j];
  }
}

__global__ __launch_bounds__(256) void k_scan3(unsigned* __restrict__ off,
                                               const unsigned* __restrict__ aux) {
  unsigned add = aux[blockIdx.x];
  int base = blockIdx.x * SCAN_B + threadIdx.x * 4;
  if (base + 3 < MKEY) {
    uint4* p = (uint4*)(off + base);
    uint4 x = *p;
    x.x += add; x.y += add; x.z += add; x.w += add;
    *p = x;
  } else {
    for (int j = 0; j < 4; ++j)
      if (base + j < MKEY) off[base + j] += add;
  }
}

// ---- scatter (src, ew) into sorted order; off becomes segment ENDs ----
__global__ __launch_bounds__(256) void k_scatter(const int* __restrict__ ei,
                                                 const float* __restrict__ ew,
                                                 unsigned* __restrict__ off,
                                                 unsigned* __restrict__ spack,
                                                 float* __restrict__ sewt) {
  int t = blockIdx.x * 256 + threadIdx.x;
  if (t >= TOT_E) return;
  int r = t / E_EDGE, e = t - r * E_EDGE;
  int tgt = ei[(r * 2 + 1) * E_EDGE + e];
  int src = ei[(r * 2) * E_EDGE + e];
  float w = ew[t];
  unsigned pos = atomicAdd(&off[r * N_ENT + tgt], 1u);
  spack[pos] = (unsigned)src;
  sewt[pos] = w;
}

// ---- fused main: 512 threads, 64 targets/block, wave w owns rows w*8..w*8+7 ----
__global__ __launch_bounds__(512, 2) void k_main(const unsigned short* __restrict__ xh,
                                                 const unsigned short* __restrict__ wf,
                                                 const unsigned short* __restrict__ bbf,
                                                 const unsigned* __restrict__ counts,
                                                 const unsigned* __restrict__ off_end,
                                                 const unsigned* __restrict__ spack,
                                                 const float* __restrict__ sewt,
                                                 float* __restrict__ out) {
  __shared__ __align__(16) unsigned char As[64 * 512];   // 64x256 bf16 tile, XOR-swizzled
  int n0 = blockIdx.x * 64;
  int tid = threadIdx.x;
  int w = tid >> 6, lane = tid & 63;
  int lm = lane & 15, lk = lane >> 4;
  int rbase = (w >> 2) * 32;          // wave's 32-row half for MFMA
  int cbase = (w & 3) * 4;            // wave's 4 nb columns (64 cols)

  f32x4 acc[2][4] = {};

  // ---- self phase: A-frags direct from global bf16 X ----
  {
    const unsigned short* wfb = wf + 8 * 65536;
#pragma unroll
    for (int kb = 0; kb < 8; ++kb) {
      u16x8 a[2], b[4];
#pragma unroll
      for (int mi = 0; mi < 2; ++mi)
        a[mi] = *(const u16x8*)(xh + (size_t)(n0 + rbase + mi * 16 + lm) * 256 + kb * 32 + lk * 8);
#pragma unroll
      for (int ni = 0; ni < 4; ++ni)
        b[ni] = *(const u16x8*)(wfb + ((kb * 16 + cbase + ni) * 64 + lane) * 8);
#pragma unroll
      for (int mi = 0; mi < 2; ++mi)
#pragma unroll
        for (int ni = 0; ni < 4; ++ni)
          acc[mi][ni] = mfma16(a[mi], b[ni], acc[mi][ni]);
    }
  }

  for (int r = 0; r < 8; ++r) {
    // ---- meta for this wave's 8 keys (uniform vector loads) ----
    int keyb = r * N_ENT + n0 + w * 8;
    uint4 c0 = *(const uint4*)(counts + keyb);
    uint4 c1 = *(const uint4*)(counts + keyb + 4);
    uint4 e0 = *(const uint4*)(off_end + keyb);
    uint4 e1 = *(const uint4*)(off_end + keyb + 4);
    unsigned cnt[8] = {c0.x, c0.y, c0.z, c0.w, c1.x, c1.y, c1.z, c1.w};
    unsigned end8[8] = {e0.x, e0.y, e0.z, e0.w, e1.x, e1.y, e1.z, e1.w};
    unsigned st[8];
#pragma unroll
    for (int k = 0; k < 8; ++k) st[k] = end8[k] - cnt[k];
    unsigned maxc = 0;
#pragma unroll
    for (int k = 0; k < 8; ++k) maxc = maxc > cnt[k] ? maxc : cnt[k];

    // ---- register-interleaved aggregation: one edge per key per step ----
    float agg[8][4] = {};
    for (unsigned step = 0; step < maxc; ++step) {
      unsigned pk[8];
      float wt[8];
#pragma unroll
      for (int k = 0; k < 8; ++k) {
        bool v = step < cnt[k];
        unsigned ii = v ? (st[k] + step) : 0u;
        pk[k] = spack[ii];
        wt[k] = v ? sewt[ii] : 0.0f;
      }
      ushort4 xv[8];
#pragma unroll
      for (int k = 0; k < 8; ++k)
        xv[k] = *(const ushort4*)(xh + (size_t)(pk[k] & 0x3FFFFu) * 256 + lane * 4);
#pragma unroll
      for (int k = 0; k < 8; ++k) {
        float wv = wt[k];
        agg[k][0] += wv * bf2f(xv[k].x);
        agg[k][1] += wv * bf2f(xv[k].y);
        agg[k][2] += wv * bf2f(xv[k].z);
        agg[k][3] += wv * bf2f(xv[k].w);
      }
    }

    // ---- write 8 rows (bf16, swizzled), owner-exclusive, no atomics ----
#pragma unroll
    for (int k = 0; k < 8; ++k) {
      int g = w * 8 + k;
      unsigned lo = (unsigned)f2bf(agg[k][0]) | ((unsigned)f2bf(agg[k][1]) << 16);
      unsigned hi = (unsigned)f2bf(agg[k][2]) | ((unsigned)f2bf(agg[k][3]) << 16);
      int wb = ((g * 512 + (lane >> 1) * 16) ^ ((g & 7) << 4)) + (lane & 1) * 8;
      *(uint2*)(As + wb) = make_uint2(lo, hi);
    }
    __syncthreads();

    // ---- MFMA from As + wf[r] ----
    const unsigned short* wfb = wf + r * 65536;
#pragma unroll
    for (int kb = 0; kb < 8; ++kb) {
      u16x8 a[2], b[4];
#pragma unroll
      for (int mi = 0; mi < 2; ++mi) {
        int row = rbase + mi * 16 + lm;
        int byt = (row * 512 + kb * 64 + lk * 16) ^ ((row & 7) << 4);
        a[mi] = *(const u16x8*)(As + byt);
      }
#pragma unroll
      for (int ni = 0; ni < 4; ++ni)
        b[ni] = *(const u16x8*)(wfb + ((kb * 16 + cbase + ni) * 64 + lane) * 8);
#pragma unroll
      for (int mi = 0; mi < 2; ++mi)
#pragma unroll
        for (int ni = 0; ni < 4; ++ni)
          acc[mi][ni] = mfma16(a[mi], b[ni], acc[mi][ni]);
    }
    __syncthreads();
  }

  // ---- bias via presence MFMA: P[64x8] @ bias[8x256] ----
  {
    u16x8 bb[4];
#pragma unroll
    for (int ni = 0; ni < 4; ++ni)
      bb[ni] = *(const u16x8*)(bbf + ((cbase + ni) * 64 + lane) * 8);
#pragma unroll
    for (int mi = 0; mi < 2; ++mi) {
      u16x8 pa = {};
      if (lk == 0) {
        int n = n0 + rbase + mi * 16 + lm;
#pragma unroll
        for (int r = 0; r < 8; ++r)
          pa[r] = counts[r * N_ENT + n] ? 0x3F80 : 0;
      }
#pragma unroll
      for (int ni = 0; ni < 4; ++ni)
        acc[mi][ni] = mfma16(pa, bb[ni], acc[mi][ni]);
    }
  }

  // ---- epilogue ----
#pragma unroll
  for (int mi = 0; mi < 2; ++mi)
#pragma unroll
    for (int ni = 0; ni < 4; ++ni) {
      int col = (w & 3) * 64 + ni * 16 + lm;
#pragma unroll
      for (int j = 0; j < 4; ++j) {
        int row = n0 + rbase + mi * 16 + lk * 4 + j;
        out[row * 256 + col] = acc[mi][ni][j];
      }
    }
}

extern "C" void kernel_launch(void* const* d_in, const int* in_sizes, int n_in,
                              void* d_out, int out_size, void* d_ws, size_t ws_size,
                              hipStream_t stream) {
  const float* x = (const float*)d_in[0];
  const float* relw = (const float*)d_in[1];
  const float* selfw = (const float*)d_in[2];
  const float* bias = (const float*)d_in[3];
  const int* ei = (const int*)d_in[4];
  const float* ew = (const float*)d_in[5];
  float* out = (float*)d_out;

  char* ws = (char*)d_ws;
  unsigned short* xh = (unsigned short*)ws;                          // 102,400,000
  unsigned short* wf = (unsigned short*)(ws + 102400000);            //   1,179,648
  unsigned short* bbf = (unsigned short*)(ws + 103579648);           //      16,384
  unsigned* counts = (unsigned*)(ws + 103596032);                    //   6,400,000
  unsigned* offs = (unsigned*)(ws + 109996032);                      //   6,400,000
  unsigned* aux = (unsigned*)(ws + 116396032);                       //       8,192
  unsigned* spack = (unsigned*)(ws + 116404224);                     //   4,800,000
  float* sewt = (float*)(ws + 121204224);                            //   4,800,000

  hipMemsetAsync(counts, 0, (size_t)MKEY * 4, stream);
  k_cvt_x<<<(N_ENT * D) / 2048, 256, 0, stream>>>(x, xh);
  k_cvt_w<<<288, 256, 0, stream>>>(relw, selfw, wf);
  k_cvt_bias<<<4, 256, 0, stream>>>(bias, bbf);
  k_hist<<<(TOT_E + 255) / 256, 256, 0, stream>>>(ei, counts);
  k_scan1<<<NBLK_SCAN, 256, 0, stream>>>(counts, offs, aux);
  k_scan2<<<1, 256, 0, stream>>>(aux);
  k_scan3<<<NBLK_SCAN, 256, 0, stream>>>(offs, aux);
  k_scatter<<<(TOT_E + 255) / 256, 256, 0, stream>>>(ei, ew, offs, spack, sewt);
  k_main<<<N_ENT / 64, 512, 0, stream>>>(xh, wf, bbf, counts, offs, spack, sewt, out);
}